// Round 1
// baseline (2918.070 us; speedup 1.0000x reference)
//
#include <hip/hip_runtime.h>

typedef __bf16 bf16;
typedef __bf16 bf16x8 __attribute__((ext_vector_type(8)));
typedef __bf16 bf16x4 __attribute__((ext_vector_type(4)));
typedef float  f32x4  __attribute__((ext_vector_type(4)));

// async global->LDS, 16B per lane. LDS dest must be lane-linear within the wave.
__device__ __forceinline__ void async16(const bf16* g, bf16* l) {
  __builtin_amdgcn_global_load_lds(
      (__attribute__((address_space(1))) void*)(void*)(const_cast<bf16*>(g)),
      (__attribute__((address_space(3))) void*)(void*)l,
      16, 0, 0);
}

// ---------------- elementwise converts / transposes / gathers ----------------

__global__ void cvt_bf16(const float* __restrict__ s, bf16* __restrict__ d, int n) {
  int i = blockIdx.x * blockDim.x + threadIdx.x;
  int stride = gridDim.x * blockDim.x;
  for (int k = i; k < n; k += stride) d[k] = (bf16)s[k];
}

// dst[c, r] = src[r, c]; src is R x C f32 (row-major), dst is C x R bf16.
__global__ void transpose_to_bf16(const float* __restrict__ src, bf16* __restrict__ dst,
                                  int R, int C) {
  __shared__ float tile[32][33];
  int c0 = blockIdx.x * 32, r0 = blockIdx.y * 32;
  int tx = threadIdx.x, ty = threadIdx.y;
#pragma unroll
  for (int k = 0; k < 32; k += 8)
    tile[ty + k][tx] = src[(size_t)(r0 + ty + k) * C + (c0 + tx)];
  __syncthreads();
#pragma unroll
  for (int k = 0; k < 32; k += 8)
    dst[(size_t)(c0 + ty + k) * R + (r0 + tx)] = (bf16)tile[tx][ty + k];
}

// X[r = t*64+b, :] = bf16(emb[tokens[b,t], :]), rows >= 3008 zeroed (M padded to 3072)
__global__ void gather_emb(const int* __restrict__ tokens, const float* __restrict__ emb,
                           bf16* __restrict__ X) {
  int r = blockIdx.x;
  int tid = threadIdx.x;
  if (r < 3008) {
    int t = r >> 6, b = r & 63;
    int tok = tokens[b * 47 + t];
    const float* e = emb + (size_t)tok * 512;
    for (int k = tid; k < 512; k += 128) X[(size_t)r * 512 + k] = (bf16)e[k];
  } else {
    for (int k = tid; k < 512; k += 128) X[(size_t)r * 512 + k] = (bf16)0.f;
  }
}

// S0[b, 0:1024] = bf16(enc_h), S0[b, 1024:2048] = 0, cbuf = enc_c
__global__ void init_state(const float* __restrict__ enc_h, const float* __restrict__ enc_c,
                           bf16* __restrict__ S0, float* __restrict__ cbuf) {
  int i = blockIdx.x * 256 + threadIdx.x;   // 0..65535
  int b = i >> 10, u = i & 1023;
  S0[(size_t)b * 2048 + u]        = (bf16)enc_h[i];
  S0[(size_t)b * 2048 + 1024 + u] = (bf16)0.f;
  cbuf[i] = enc_c[i];
}

// ---------------- generic bt-GEMM: C[M,N] = A[M,K] @ B[N,K]^T ----------------
// m97 structure: 128x128 tile, BK=32, 4 waves (2x2), 64x64 per wave, 16x16x32 bf16 MFMA.
// MODE 0: bf16 C      MODE 1: bf16 C, += RT[r,c] for c<1024 (W12T build)
// MODE 2: f32 C, += aux[c] (bias)     MODE 3: logits scatter, += aux[c], mask r<3008
// MODE 4: plain f32 C
template <int MODE>
__global__ __launch_bounds__(256) void gemm_bt(
    const bf16* __restrict__ A, int lda,
    const bf16* __restrict__ B, int ldb, int K,
    void* __restrict__ C, int ldc,
    const void* __restrict__ aux) {
  __shared__ bf16 As[128 * 32];
  __shared__ bf16 Bs[128 * 32];
  const int tid = threadIdx.x;
  const int wave = tid >> 6, lane = tid & 63;
  const int wm = wave >> 1, wn = wave & 1;
  const int quad = lane >> 4, l16 = lane & 15;
  const size_t r0 = (size_t)blockIdx.y * 128;
  const size_t c0 = (size_t)blockIdx.x * 128;

  f32x4 acc[4][4] = {};

  for (int k0 = 0; k0 < K; k0 += 32) {
#pragma unroll
    for (int j = 0; j < 2; ++j) {
      int seg = j * 256 + tid;
      int row = seg >> 2, ks = seg & 3;
      async16(A + (r0 + row) * (size_t)lda + k0 + ks * 8, As + seg * 8);
    }
#pragma unroll
    for (int j = 0; j < 2; ++j) {
      int seg = j * 256 + tid;
      int row = seg >> 2, ks = seg & 3;
      async16(B + (c0 + row) * (size_t)ldb + k0 + ks * 8, Bs + seg * 8);
    }
    __syncthreads();
    bf16x8 af[4], bfr[4];
#pragma unroll
    for (int mi = 0; mi < 4; ++mi)
      af[mi] = *(const bf16x8*)(As + (wm * 64 + mi * 16 + l16) * 32 + quad * 8);
#pragma unroll
    for (int ni = 0; ni < 4; ++ni)
      bfr[ni] = *(const bf16x8*)(Bs + (wn * 64 + ni * 16 + l16) * 32 + quad * 8);
#pragma unroll
    for (int mi = 0; mi < 4; ++mi)
#pragma unroll
      for (int ni = 0; ni < 4; ++ni)
        acc[mi][ni] = __builtin_amdgcn_mfma_f32_16x16x32_bf16(af[mi], bfr[ni], acc[mi][ni], 0, 0, 0);
    __syncthreads();
  }

#pragma unroll
  for (int mi = 0; mi < 4; ++mi)
#pragma unroll
    for (int ni = 0; ni < 4; ++ni)
#pragma unroll
      for (int reg = 0; reg < 4; ++reg) {
        size_t r = r0 + wm * 64 + mi * 16 + quad * 4 + reg;
        size_t c = c0 + wn * 64 + ni * 16 + l16;
        float v = acc[mi][ni][reg];
        if (MODE == 0) {
          ((bf16*)C)[r * ldc + c] = (bf16)v;
        } else if (MODE == 1) {
          if (c < 1024) v += (float)((const bf16*)aux)[r * 1024 + c];
          ((bf16*)C)[r * ldc + c] = (bf16)v;
        } else if (MODE == 2) {
          v += ((const float*)aux)[c];
          ((float*)C)[r * ldc + c] = v;
        } else if (MODE == 3) {
          if (r < 3008) {
            size_t t = r >> 6, b = r & 63;
            ((float*)C)[(b * 47 + t) * (size_t)32000 + c] = v + ((const float*)aux)[c];
          }
        } else {
          ((float*)C)[r * ldc + c] = v;
        }
      }
}

// ---------------- per-step kernel A: z-GEMM + LSTM gates (fused) ----------------
// z[64, 4096] = precomp_t + Sin[64,K] @ Bt[4096,K]^T(selected rows); gates -> h2, c2.
// Grid 128 blocks: block p owns gate columns j = p*8 + s (s<8) for all 4 gates.
// Block 128 threads = 2 waves; wave w computes cols n_local = w*16+l16 of 32.
__global__ __launch_bounds__(128) void step_gates(
    const bf16* __restrict__ Sin,      // [64, 2048]
    const bf16* __restrict__ Bt,       // W12T [4096,2048] or RT [4096,1024]
    int ldb, int K,
    const float* __restrict__ precomp_t,  // [64, 4096]
    float* __restrict__ cbuf,          // [64, 1024]
    bf16* __restrict__ Sout,           // [64, 2048] (h2 part)
    bf16* __restrict__ HC_t)           // [64, 2048] (h2 part)
{
  __shared__ bf16 As[64 * 32];   // 4 KB
  __shared__ bf16 Bs[32 * 32];   // 2 KB
  __shared__ float zs[64 * 32];  // 8 KB
  const int tid = threadIdx.x;
  const int wave = tid >> 6, lane = tid & 63;
  const int quad = lane >> 4, l16 = lane & 15;
  const int p = blockIdx.x;      // 0..127

  f32x4 acc[4] = {};

  for (int k0 = 0; k0 < K; k0 += 32) {
#pragma unroll
    for (int j = 0; j < 2; ++j) {
      int seg = j * 128 + tid;
      int row = seg >> 2, ks = seg & 3;
      async16(Sin + (size_t)row * 2048 + k0 + ks * 8, As + seg * 8);
    }
    {
      int nl = tid >> 2, ks = tid & 3;
      int gate = nl >> 3, s = nl & 7;
      int ng = gate * 1024 + p * 8 + s;
      async16(Bt + (size_t)ng * ldb + k0 + ks * 8, Bs + tid * 8);
    }
    __syncthreads();
    bf16x8 bfr = *(const bf16x8*)(Bs + (wave * 16 + l16) * 32 + quad * 8);
#pragma unroll
    for (int mi = 0; mi < 4; ++mi) {
      bf16x8 afr = *(const bf16x8*)(As + (mi * 16 + l16) * 32 + quad * 8);
      acc[mi] = __builtin_amdgcn_mfma_f32_16x16x32_bf16(afr, bfr, acc[mi], 0, 0, 0);
    }
    __syncthreads();
  }

  {
    int nl = wave * 16 + l16;           // 0..31
    int gate = nl >> 3, s = nl & 7;
#pragma unroll
    for (int mi = 0; mi < 4; ++mi)
#pragma unroll
      for (int reg = 0; reg < 4; ++reg) {
        int row = mi * 16 + quad * 4 + reg;
        float z = acc[mi][reg] + precomp_t[(size_t)row * 4096 + gate * 1024 + p * 8 + s];
        zs[row * 32 + nl] = z;
      }
  }
  __syncthreads();

#pragma unroll
  for (int ii = 0; ii < 4; ++ii) {
    int idx = ii * 128 + tid;           // 0..511 -> (b, s2)
    int b = idx >> 3, s2 = idx & 7;
    int j = p * 8 + s2;
    float iv = zs[b * 32 + s2];
    float fv = zs[b * 32 + 8 + s2];
    float gv = zs[b * 32 + 16 + s2];
    float ov = zs[b * 32 + 24 + s2];
    float c_old = cbuf[b * 1024 + j];
    float ig = 1.f / (1.f + __expf(-iv));
    float fg = 1.f / (1.f + __expf(-fv));
    float og = 1.f / (1.f + __expf(-ov));
    float c2 = fg * c_old + ig * tanhf(gv);
    float h2 = og * tanhf(c2);
    cbuf[b * 1024 + j] = c2;
    bf16 hb = (bf16)h2;
    Sout[(size_t)b * 2048 + j] = hb;
    HC_t[(size_t)b * 2048 + j] = hb;
  }
}

// ---------------- per-step kernel B: Luong attention ----------------
// One block per batch b: score = h2 . keys[b], softmax, ctx = align . memory[b].
__global__ __launch_bounds__(256) void step_attn(
    const bf16* __restrict__ Sh,       // Sout: h2 at [b*2048 + 0..1023], ctx written back
    const float* __restrict__ keys,    // [4096, 1024] f32
    const bf16* __restrict__ memB,     // [4096, 1024] bf16
    bf16* __restrict__ HC_t)           // [64, 2048] (ctx part)
{
  __shared__ float h2s[1024];
  __shared__ float sm[64];
  const int b = blockIdx.x;
  const int tid = threadIdx.x;
  const int wave = tid >> 6, lane = tid & 63;

#pragma unroll
  for (int j = 0; j < 4; ++j) {
    int u = j * 256 + tid;
    h2s[u] = (float)Sh[(size_t)b * 2048 + u];
  }
  __syncthreads();

  for (int ii = 0; ii < 16; ++ii) {
    int it = wave * 16 + ii;
    const float* krow = keys + ((size_t)b * 64 + it) * 1024;
    float pr = 0.f;
#pragma unroll
    for (int q = 0; q < 16; ++q) {
      int u = q * 64 + lane;
      pr += h2s[u] * krow[u];
    }
#pragma unroll
    for (int off = 32; off > 0; off >>= 1) pr += __shfl_xor(pr, off);
    if (lane == 0) sm[it] = pr;
  }
  __syncthreads();

  if (tid < 64) {
    float s = sm[tid];
    float mx = s;
#pragma unroll
    for (int off = 32; off > 0; off >>= 1) mx = fmaxf(mx, __shfl_xor(mx, off));
    float e = __expf(s - mx);
    float sum = e;
#pragma unroll
    for (int off = 32; off > 0; off >>= 1) sum += __shfl_xor(sum, off);
    sm[tid] = e / sum;
  }
  __syncthreads();

  int u0 = tid * 4;
  float a0 = 0.f, a1 = 0.f, a2 = 0.f, a3 = 0.f;
  for (int i = 0; i < 64; ++i) {
    float al = sm[i];
    bf16x4 m4 = *(const bf16x4*)(memB + ((size_t)b * 64 + i) * 1024 + u0);
    a0 += al * (float)m4[0];
    a1 += al * (float)m4[1];
    a2 += al * (float)m4[2];
    a3 += al * (float)m4[3];
  }
  bf16* so = (bf16*)Sh;
  so[(size_t)b * 2048 + 1024 + u0 + 0] = (bf16)a0;
  so[(size_t)b * 2048 + 1024 + u0 + 1] = (bf16)a1;
  so[(size_t)b * 2048 + 1024 + u0 + 2] = (bf16)a2;
  so[(size_t)b * 2048 + 1024 + u0 + 3] = (bf16)a3;
  HC_t[(size_t)b * 2048 + 1024 + u0 + 0] = (bf16)a0;
  HC_t[(size_t)b * 2048 + 1024 + u0 + 1] = (bf16)a1;
  HC_t[(size_t)b * 2048 + 1024 + u0 + 2] = (bf16)a2;
  HC_t[(size_t)b * 2048 + 1024 + u0 + 3] = (bf16)a3;
}

// ---------------- driver ----------------

extern "C" void kernel_launch(void* const* d_in, const int* in_sizes, int n_in,
                              void* d_out, int out_size, void* d_ws, size_t ws_size,
                              hipStream_t stream) {
  const int*   tokens = (const int*)d_in[0];
  const float* memory = (const float*)d_in[1];
  const float* enc_h  = (const float*)d_in[2];
  const float* enc_c  = (const float*)d_in[3];
  const float* emb    = (const float*)d_in[4];
  const float* Wm     = (const float*)d_in[5];
  const float* Wa     = (const float*)d_in[6];
  const float* lstm_k = (const float*)d_in[7];
  const float* lstm_r = (const float*)d_in[8];
  const float* lstm_b = (const float*)d_in[9];
  const float* fc_w   = (const float*)d_in[10];
  const float* fc_b   = (const float*)d_in[11];
  float* out = (float*)d_out;

  // scratch inside d_out (dead before the final logits GEMM writes out)
  char* ob = (char*)d_out;
  size_t off = 0;
  auto alloc_o = [&](size_t bytes) { char* q = ob + off; off += bytes; return q; };
  bf16*  memB    = (bf16*)alloc_o(8388608);        // [4096,1024] bf16
  float* keys    = (float*)alloc_o(16777216);      // [4096,1024] f32
  bf16*  WaB     = (bf16*)alloc_o(4194304);        // [2048,1024] bf16
  bf16*  WmT     = (bf16*)alloc_o(2097152);        // [1024,1024]
  bf16*  KpT     = (bf16*)alloc_o(8388608);        // [4096,1024]
  bf16*  KxT     = (bf16*)alloc_o(4194304);        // [4096,512]
  bf16*  RT      = (bf16*)alloc_o(8388608);        // [4096,1024]
  bf16*  WaT     = (bf16*)alloc_o(4194304);        // [1024,2048]
  bf16*  X       = (bf16*)alloc_o(3145728);        // [3072,512]
  bf16*  W12T    = (bf16*)alloc_o(16777216);       // [4096,2048]
  bf16*  S0      = (bf16*)alloc_o(262144);         // [64,2048]
  bf16*  S1      = (bf16*)alloc_o(262144);
  float* cbuf    = (float*)alloc_o(262144);        // [64,1024]
  bf16*  HC      = (bf16*)alloc_o(12582912);       // [3072,2048]
  float* precomp = (float*)alloc_o(50331648);      // [3072,4096] f32

  // d_ws: only what is live during the final logits GEMM
  char* wb = (char*)d_ws;
  bf16* fcwT  = (bf16*)(wb);                       // [32000,1024] bf16 (65,536,000 B)
  bf16* attnb = (bf16*)(wb + 65536000);            // [3072,1024] bf16

  dim3 tb(32, 8);

  // precompute / converts
  cvt_bf16<<<2048, 256, 0, stream>>>(memory, memB, 4194304);
  cvt_bf16<<<2048, 256, 0, stream>>>(Wa, WaB, 2097152);
  transpose_to_bf16<<<dim3(32, 32), tb, 0, stream>>>(Wm, WmT, 1024, 1024);
  transpose_to_bf16<<<dim3(128, 32), tb, 0, stream>>>(lstm_k + (size_t)512 * 4096, KpT, 1024, 4096);
  transpose_to_bf16<<<dim3(128, 16), tb, 0, stream>>>(lstm_k, KxT, 512, 4096);
  transpose_to_bf16<<<dim3(128, 32), tb, 0, stream>>>(lstm_r, RT, 1024, 4096);
  transpose_to_bf16<<<dim3(32, 64), tb, 0, stream>>>(Wa, WaT, 2048, 1024);
  transpose_to_bf16<<<dim3(1000, 32), tb, 0, stream>>>(fc_w, fcwT, 1024, 32000);
  gather_emb<<<3072, 128, 0, stream>>>(tokens, emb, X);
  init_state<<<256, 256, 0, stream>>>(enc_h, enc_c, S0, cbuf);

  // keys = memory @ Wm  (f32 out)
  gemm_bt<4><<<dim3(8, 32), 256, 0, stream>>>(memB, 1024, WmT, 1024, 1024, keys, 1024, nullptr);
  // W12T[n, m] = (Wa@Kp)[m, n] + (m<1024 ? lstm_r[m, n] : 0)   (bf16 out)
  gemm_bt<1><<<dim3(16, 32), 256, 0, stream>>>(KpT, 1024, WaB, 1024, 1024, W12T, 2048, RT);
  // precomp = X @ lstm_k[0:512] + lstm_b   (f32 out)
  gemm_bt<2><<<dim3(32, 24), 256, 0, stream>>>(X, 512, KxT, 512, 512, precomp, 4096, lstm_b);

  // recurrence: 2 kernels per step
  for (int t = 0; t < 47; ++t) {
    const bf16* Sin = (t & 1) ? S1 : S0;
    bf16* Sout = (t & 1) ? S0 : S1;
    const bf16* Bt = (t == 0) ? RT : W12T;
    int ldb = (t == 0) ? 1024 : 2048;
    int K = (t == 0) ? 1024 : 2048;
    bf16* HC_t = HC + (size_t)t * 64 * 2048;
    step_gates<<<128, 128, 0, stream>>>(Sin, Bt, ldb, K,
                                        precomp + (size_t)t * 64 * 4096, cbuf, Sout, HC_t);
    step_attn<<<64, 256, 0, stream>>>(Sout, keys, memB, HC_t);
  }

  // attn_all = HC @ Wa   (bf16 out)
  gemm_bt<0><<<dim3(8, 24), 256, 0, stream>>>(HC, 2048, WaT, 2048, 2048, attnb, 1024, nullptr);
  // logits = attn_all @ fc_w + fc_b, scattered to out[b, t, v]
  gemm_bt<3><<<dim3(250, 24), 256, 0, stream>>>(attnb, 1024, fcwT, 1024, 1024, out, 32000, fc_b);

  (void)in_sizes; (void)n_in; (void)out_size; (void)ws_size;
}